// Round 8
// baseline (207.042 us; speedup 1.0000x reference)
//
#include <hip/hip_runtime.h>
#include <hip/hip_bf16.h>

#define C_DIM 100000
#define NROW 512
#define DDIM 512
#define BN 64
#define NPANEL 1563            // ceil(C_DIM/64)
#define LFS 67                 // padded f32 row stride for bounce buffer

typedef __attribute__((ext_vector_type(4))) float f32x4;
typedef __attribute__((ext_vector_type(8))) short bf16x8;
typedef __attribute__((ext_vector_type(4))) float f32acc;

// ---------------- kernel 1: norm2[d] = sum_c W[d][c]^2 --------------------------
__global__ __launch_bounds__(256) void cf_knorm(const float* __restrict__ W,
                                                float* __restrict__ norm2) {
    const int d = blockIdx.x;
    const float* row = W + (size_t)d * C_DIM;
    float s = 0.f;
    for (int c4 = threadIdx.x; c4 < C_DIM / 4; c4 += 256) {
        f32x4 v = *(const f32x4*)(row + c4 * 4);
        s += v.x * v.x + v.y * v.y + v.z * v.z + v.w * v.w;
    }
    #pragma unroll
    for (int off = 32; off; off >>= 1) s += __shfl_down(s, off, 64);
    __shared__ float wsum[4];
    if ((threadIdx.x & 63) == 0) wsum[threadIdx.x >> 6] = s;
    __syncthreads();
    if (threadIdx.x == 0) norm2[d] = wsum[0] + wsum[1] + wsum[2] + wsum[3];
}

// ------- kernel 2: xs2 = bf16(x * rsqrt(norm2)) fragment-tiled ------------------
// xs2[((row>>4)*64 + k8)*128 + (row&15)*8 + e]  (row=0..511, col=k8*8+e)
__global__ __launch_bounds__(256) void cf_kxs2(const float* __restrict__ x,
                                               const float* __restrict__ norm2,
                                               __hip_bfloat16* __restrict__ xs2) {
    const int idx = blockIdx.x * 256 + threadIdx.x;
    const int row = idx >> 6;
    const int k8  = idx & 63;
    const float* xp = x + (size_t)row * DDIM + k8 * 8;
    f32x4 v0 = *(const f32x4*)(xp);
    f32x4 v1 = *(const f32x4*)(xp + 4);
    union { __hip_bfloat16 h[8]; bf16x8 v; } p;
    #pragma unroll
    for (int e = 0; e < 4; ++e) p.h[e]     = __float2bfloat16(v0[e] * rsqrtf(norm2[k8 * 8 + e]));
    #pragma unroll
    for (int e = 0; e < 4; ++e) p.h[4 + e] = __float2bfloat16(v1[e] * rsqrtf(norm2[k8 * 8 + 4 + e]));
    *(bf16x8*)(xs2 + ((size_t)((row >> 4) * 64 + k8) * 128 + (row & 15) * 8)) = p.v;
}

// ---------------- kernel 3: target logits, cos_m, final -------------------------
__global__ __launch_bounds__(64) void cf_ktgt(const float* __restrict__ x,
                                              const float* __restrict__ W,
                                              const float* __restrict__ norm2,
                                              const int* __restrict__ label,
                                              float* __restrict__ tl,
                                              float* __restrict__ cm,
                                              float* __restrict__ fl) {
    const int i = blockIdx.x;
    const int lane = threadIdx.x;
    const int lab = label[i];
    float s = 0.f;
    for (int d = lane; d < DDIM; d += 64)
        s += x[(size_t)i * DDIM + d] * rsqrtf(norm2[d]) * W[(size_t)d * C_DIM + lab];
    #pragma unroll
    for (int off = 32; off; off >>= 1) s += __shfl_down(s, off, 64);
    if (lane == 0) {
        float t = fminf(fmaxf(s, -1.f), 1.f);
        float sn = sqrtf(fmaxf(1.f - t * t, 0.f));
        float c = t * 0.8775825618903728f - sn * 0.479425538604203f; // cos(th+m)
        tl[i] = t;
        cm[i] = c;
        fl[i] = (t > -0.8775825618903728f) ? c : (t - 0.2397127693021015f);
    }
}

// ---------------- kernel 4: t = 0.01 * mean(target_logit) -----------------------
__global__ __launch_bounds__(512) void cf_kt(const float* __restrict__ tl,
                                             float* __restrict__ tout) {
    float s = tl[threadIdx.x];
    #pragma unroll
    for (int off = 32; off; off >>= 1) s += __shfl_down(s, off, 64);
    __shared__ float w[8];
    if ((threadIdx.x & 63) == 0) w[threadIdx.x >> 6] = s;
    __syncthreads();
    if (threadIdx.x == 0) {
        float tt = 0.f;
        #pragma unroll
        for (int j = 0; j < 8; ++j) tt += w[j];
        tout[0] = 0.01f * (tt / 512.0f);
    }
}

// ---------------- kernel 5: GEMM + LDS-bounced wide-granule epilogue ------------
// Stage + MFMA core identical to the verified round-4 kernel. After compute the
// 64KB LDS is reused: 4 chunks of 128 rows; owning wave-pair dumps acc (D[c][i])
// into LF[row][c] (stride 67), then all 512 threads store row-major so each
// store instruction covers 4 rows x 256B contiguous (vs 16 rows x 64B before).
__global__ __launch_bounds__(512, 4) void cf_kgemm5(
    const __hip_bfloat16* __restrict__ xs2,
    const float* __restrict__ W,
    const int* __restrict__ label,
    const float* __restrict__ cosm,
    const float* __restrict__ finl,
    const float* __restrict__ tp,
    float* __restrict__ out) {
    __shared__ __attribute__((aligned(16))) char smem[64 * 512 * 2];  // 64KB
    __hip_bfloat16* Bl = (__hip_bfloat16*)smem;
    float* LF = (float*)smem;            // [128][LFS] bounce view (34KB used)

    const int tid  = threadIdx.x;
    const int wv   = tid >> 6;
    const int lane = tid & 63;
    const int il   = lane & 15;
    const int hi   = lane >> 4;
    const int cb   = blockIdx.x * BN;

    // ---- stage full W panel f32 -> bf16 swizzled LDS image (round-4 proven) ----
    {
        const int c4 = (tid & 15) * 4;
        const int k8 = tid >> 4;
        const bool ok = (cb + c4) < C_DIM;
        #pragma unroll
        for (int kk2 = 0; kk2 < 2; ++kk2) {
            const int kb = kk2 * 256 + k8 * 8;
            f32x4 v[8];
            #pragma unroll
            for (int j = 0; j < 8; ++j) {
                if (ok) v[j] = *(const f32x4*)(W + (size_t)(kb + j) * C_DIM + cb + c4);
                else    v[j] = (f32x4){0.f, 0.f, 0.f, 0.f};
            }
            const int q = kk2 * 32 + k8;
            #pragma unroll
            for (int cc = 0; cc < 4; ++cc) {
                const int c = c4 + cc;
                union { __hip_bfloat16 h[8]; bf16x8 b; } p;
                #pragma unroll
                for (int j = 0; j < 8; ++j) p.h[j] = __float2bfloat16(v[j][cc]);
                *(bf16x8*)&Bl[c * 512 + (q ^ (c & 7)) * 8] = p.b;
            }
        }
    }
    __syncthreads();

    f32acc acc[4][4];
    #pragma unroll
    for (int m = 0; m < 4; ++m)
        #pragma unroll
        for (int n = 0; n < 4; ++n)
            acc[m][n] = (f32acc){0.f, 0.f, 0.f, 0.f};

    // ---- MFMA core (round-4 proven): barrier-free, reg ping-pong on B ----
    {
        int crow[4];
        #pragma unroll
        for (int m = 0; m < 4; ++m) crow[m] = (m * 16 + il) * 512;

        auto loadB = [&](bf16x8 (&bb)[4], int kt) {
            #pragma unroll
            for (int n = 0; n < 4; ++n)
                bb[n] = *(const bf16x8*)(xs2 + (size_t)((wv * 4 + n) * 64 + kt * 4 + hi) * 128 + il * 8);
        };
        auto step = [&](const bf16x8 (&bb)[4], int kt) {
            bf16x8 a[4];
            #pragma unroll
            for (int m = 0; m < 4; ++m) {
                const int c = m * 16 + il;
                const int q = (kt * 4 + hi) ^ (c & 7);
                a[m] = *(const bf16x8*)&Bl[crow[m] + q * 8];
            }
            #pragma unroll
            for (int m = 0; m < 4; ++m)
                #pragma unroll
                for (int n = 0; n < 4; ++n)
                    acc[m][n] = __builtin_amdgcn_mfma_f32_16x16x32_bf16(a[m], bb[n], acc[m][n], 0, 0, 0);
        };

        bf16x8 b0[4], b1[4];
        loadB(b0, 0);
        #pragma unroll
        for (int kt = 0; kt < 16; kt += 2) {
            if (kt + 1 < 16) loadB(b1, kt + 1);
            step(b0, kt);
            if (kt + 2 < 16) loadB(b0, kt + 2);
            if (kt + 1 < 16) step(b1, kt + 1);
        }
    }
    __syncthreads();   // compute done; LDS reusable

    // ---- bounced epilogue: 4 chunks of 128 rows ----
    const float t = tp[0];
    #pragma unroll 1
    for (int ch = 0; ch < 4; ++ch) {
        if ((wv >> 1) == ch) {
            const int iw = wv & 1;      // i-local base iw*64 within chunk
            #pragma unroll
            for (int n = 0; n < 4; ++n) {
                const int row = iw * 64 + n * 16 + il;
                #pragma unroll
                for (int m = 0; m < 4; ++m)
                    *(f32x4*)&LF[row * LFS + m * 16 + hi * 4] = acc[m][n];
            }
        }
        __syncthreads();
        const int c0 = cb + il * 4;
        if (c0 < C_DIM) {
            #pragma unroll
            for (int rr = 0; rr < 4; ++rr) {
                const int row = rr * 32 + wv * 4 + hi;   // 0..127
                const int i = ch * 128 + row;
                const float cmv = cosm[i];
                const float flv = finl[i];
                const int lab = label[i];
                f32x4 v = *(const f32x4*)&LF[row * LFS + il * 4];
                f32x4 o;
                #pragma unroll
                for (int r = 0; r < 4; ++r) {
                    float cz = fminf(fmaxf(v[r], -1.f), 1.f);
                    float ov = (cz > cmv) ? cz * (t + cz) : cz;
                    if (c0 + r == lab) ov = flv;
                    o[r] = ov * 64.0f;
                }
                *(f32x4*)(out + (size_t)i * C_DIM + c0) = o;
            }
        }
        __syncthreads();
    }
}

extern "C" void kernel_launch(void* const* d_in, const int* in_sizes, int n_in,
                              void* d_out, int out_size, void* d_ws, size_t ws_size,
                              hipStream_t stream) {
    const float* x   = (const float*)d_in[0];
    const float* W   = (const float*)d_in[1];
    const int* label = (const int*)d_in[2];
    float* out = (float*)d_out;

    char* ws = (char*)d_ws;
    float* norm2 = (float*)ws;             // 512 f32 (sum of squares)
    float* tl  = norm2 + 512;
    float* cm  = tl + 512;
    float* fl  = cm + 512;
    float* tsc = fl + 512;
    __hip_bfloat16* xs2 = (__hip_bfloat16*)(ws + 16384);  // 512 KB

    cf_knorm<<<DDIM, 256, 0, stream>>>(W, norm2);
    cf_kxs2<<<128, 256, 0, stream>>>(x, norm2, xs2);
    cf_ktgt<<<NROW, 64, 0, stream>>>(x, W, norm2, label, tl, cm, fl);
    cf_kt<<<1, 512, 0, stream>>>(tl, tsc);

    cf_kgemm5<<<NPANEL, 512, 0, stream>>>(xs2, W, label, cm, fl, tsc, out);
}